// Round 8
// baseline (619.886 us; speedup 1.0000x reference)
//
#include <hip/hip_runtime.h>
#include <math.h>

// Problem constants
#define HIDN 2048
#define NH   16
#define LATN 512
#define RD   32
#define DHD  128
#define CDIM 96
#define NB   2
#define SEQ  2048
#define MTOT 4096   // NB*SEQ token rows

typedef __attribute__((ext_vector_type(8))) short bf8_t;   // 8 x bf16 (4 VGPRs)
typedef __attribute__((ext_vector_type(4))) float f4_t;    // MFMA C/D frag
typedef __attribute__((ext_vector_type(4))) short s4_t;    // 4 x bf16 (8 B)

__device__ __forceinline__ short f2bf(float f) {
    union { float f; unsigned u; } x; x.f = f;
    unsigned r = x.u + 0x7fffu + ((x.u >> 16) & 1u);   // round-to-nearest-even
    return (short)(r >> 16);
}
__device__ __forceinline__ float bf2f(short s) {
    union { float f; unsigned u; } x; x.u = ((unsigned)(unsigned short)s) << 16;
    return x.f;
}
// async global->LDS, 16B per lane (still used by attention)
__device__ __forceinline__ void gload16(const void* g, void* l) {
    __builtin_amdgcn_global_load_lds(
        (const __attribute__((address_space(1))) void*)g,
        (__attribute__((address_space(3))) void*)l, 16, 0, 0);
}
// lgkmcnt(0)-only wait (vmcnt=63, expcnt=7 untouched), then hardware barrier.
// Keeps global loads in flight across the barrier (no vmcnt(0) drain).
__device__ __forceinline__ void lds_barrier() {
    __builtin_amdgcn_s_waitcnt(0xC07F);
    __builtin_amdgcn_s_barrier();
}

// 16-lane all-reduce via DPP (VALU-only)
__device__ __forceinline__ float dpp_max16(float x) {
    union { float f; int i; } a, t; a.f = x;
    t.i = __builtin_amdgcn_update_dpp(0, a.i, 0xB1,  0xF, 0xF, true); a.f = fmaxf(a.f, t.f);
    t.i = __builtin_amdgcn_update_dpp(0, a.i, 0x4E,  0xF, 0xF, true); a.f = fmaxf(a.f, t.f);
    t.i = __builtin_amdgcn_update_dpp(0, a.i, 0x124, 0xF, 0xF, true); a.f = fmaxf(a.f, t.f);
    t.i = __builtin_amdgcn_update_dpp(0, a.i, 0x128, 0xF, 0xF, true); a.f = fmaxf(a.f, t.f);
    return a.f;
}
__device__ __forceinline__ float dpp_sum16(float x) {
    union { float f; int i; } a, t; a.f = x;
    t.i = __builtin_amdgcn_update_dpp(0, a.i, 0xB1,  0xF, 0xF, true); a.f += t.f;
    t.i = __builtin_amdgcn_update_dpp(0, a.i, 0x4E,  0xF, 0xF, true); a.f += t.f;
    t.i = __builtin_amdgcn_update_dpp(0, a.i, 0x124, 0xF, 0xF, true); a.f += t.f;
    t.i = __builtin_amdgcn_update_dpp(0, a.i, 0x128, 0xF, 0xF, true); a.f += t.f;
    return a.f;
}

// ---------------------------------------------------------------------------
// f32 -> bf16 conversion for x + all 8 weights, one launch.
// ---------------------------------------------------------------------------
__global__ __launch_bounds__(256)
void cvt_all(const float* __restrict__ x,  const float* __restrict__ w0,
             const float* __restrict__ w1, const float* __restrict__ w2,
             const float* __restrict__ w3, const float* __restrict__ w4,
             const float* __restrict__ w5, const float* __restrict__ w6,
             const float* __restrict__ w7,
             short* xb, short* o0, short* o1, short* o2, short* o3,
             short* o4, short* o5, short* o6, short* o7)
{
    int bid = blockIdx.x;
    const float* src; short* dst; int rel;
    if      (bid < 4096) { src = x;  dst = xb; rel = bid; }
    else if (bid < 4608) { src = w0; dst = o0; rel = bid - 4096; }
    else if (bid < 4992) { src = w1; dst = o1; rel = bid - 4608; }
    else if (bid < 5120) { src = w2; dst = o2; rel = bid - 4992; }
    else if (bid < 5632) { src = w3; dst = o3; rel = bid - 5120; }
    else if (bid < 6016) { src = w4; dst = o4; rel = bid - 5632; }
    else if (bid < 6048) { src = w5; dst = o5; rel = bid - 6016; }
    else if (bid < 6560) { src = w6; dst = o6; rel = bid - 6048; }
    else                 { src = w7; dst = o7; rel = bid - 6560; }
    int base = rel * 2048 + threadIdx.x * 8;
    float4 a = *(const float4*)(src + base);
    float4 b = *(const float4*)(src + base + 4);
    s4_t r0 = { f2bf(a.x), f2bf(a.y), f2bf(a.z), f2bf(a.w) };
    s4_t r1 = { f2bf(b.x), f2bf(b.y), f2bf(b.z), f2bf(b.w) };
    *(s4_t*)(dst + base)     = r0;
    *(s4_t*)(dst + base + 4) = r1;
}

// ---------------------------------------------------------------------------
// bf16 MFMA NT GEMM, register-staged pipeline + raw barrier (no vmcnt drain).
// 128x128 tile, BK=32, 4 waves, 4x4 16x16x32 frags.
// Loads: global->VGPR (distance-2 prefetch, compiler inserts precise vmcnt);
// VGPR->LDS via ds_write_b128 into the same swizzled chunk layout;
// barrier = s_waitcnt lgkmcnt(0) + s_barrier, so global loads stay in flight.
// ---------------------------------------------------------------------------
#define EPI_DOWN 0
#define EPI_UP   1
#define EPI_WO   2

template<int KTOT, int EPI>
__global__ __launch_bounds__(256)
void gemm_t(const short* __restrict__ A, const short* __restrict__ W,
            const short* __restrict__ W2,
            void* __restrict__ o1, void* __restrict__ o2,
            void* __restrict__ o3, void* __restrict__ o4,
            const float* __restrict__ bias)
{
    __shared__ short As[2][4096];
    __shared__ short Bs[2][4096];
    const int tid  = threadIdx.x;
    const int w    = tid >> 6;
    const int lane = tid & 63;
    const int l16  = lane & 15;
    const int quad = lane >> 4;
    const int m0 = blockIdx.x * 128;
    int n0 = blockIdx.y * 128;
    const int wm = (w & 1) * 64;
    const int wn = (w >> 1) * 64;

    const short* Ap = A;
    const short* Wp = W;
    int lda, Nrow, job = 0;
    if (EPI == EPI_DOWN) { lda = 2048; Nrow = 1056; }
    if (EPI == EPI_WO)   { lda = 2048; Nrow = 2048; }
    if (EPI == EPI_UP) {
        lda = 1024;
        if (blockIdx.y < 16) { Nrow = 2048; }
        else { job = 1; Ap = A + 512; Wp = W2; n0 = ((int)blockIdx.y - 16) * 128; Nrow = 3584; }
    }

    int srow[2], skc[2], ldso[2];
#pragma unroll
    for (int j = 0; j < 2; ++j) {
        int c = (w * 32 + j * 16) * 4 + lane;
        srow[j] = c >> 2;
        skc[j]  = (c & 3) ^ (srow[j] & 3);
        ldso[j] = c * 8;                  // short offset = chunk*8
    }
    const int xq = quad ^ (l16 & 3);

    // register staging, 2 stages (tile t+2 loaded at iter t)
    int4 rA[2][2], rB[2][2];
    const short* arow[2]; const short* brow[2];
#pragma unroll
    for (int j = 0; j < 2; ++j) {
        arow[j] = Ap + (size_t)(m0 + srow[j]) * lda + skc[j] * 8;
        int gn = n0 + srow[j]; if (gn >= Nrow) gn = Nrow - 1;
        brow[j] = Wp + (size_t)gn * KTOT + skc[j] * 8;
    }
    auto loadrg = [&](int k0, int st) {
#pragma unroll
        for (int j = 0; j < 2; ++j) {
            rA[st][j] = *(const int4*)(arow[j] + k0);
            rB[st][j] = *(const int4*)(brow[j] + k0);
        }
    };
    auto wlds = [&](int buf, int st) {
#pragma unroll
        for (int j = 0; j < 2; ++j) {
            *(int4*)&As[buf][ldso[j]] = rA[st][j];
            *(int4*)&Bs[buf][ldso[j]] = rB[st][j];
        }
    };

    f4_t acc[4][4];
#pragma unroll
    for (int i = 0; i < 4; ++i)
#pragma unroll
        for (int j = 0; j < 4; ++j) acc[i][j] = (f4_t){0.f, 0.f, 0.f, 0.f};

    const int nk = KTOT / 32;   // >= 16 always
    loadrg(0, 0);
    loadrg(32, 1);
    wlds(0, 0);

    for (int t = 0; t < nk; ++t) {
        const int cur = t & 1;
        lds_barrier();                       // LDS[cur] ready; LDS[cur^1] free
        if (t + 1 < nk) wlds(cur ^ 1, (t + 1) & 1);   // precise vmcnt wait on stage regs
        if (t + 2 < nk) loadrg((t + 2) * 32, t & 1);  // refill freed stage
        bf8_t af[4], bfr[4];
#pragma unroll
        for (int i = 0; i < 4; ++i)
            af[i] = *(const bf8_t*)&As[cur][((wm + i * 16 + l16) * 4 + xq) * 8];
#pragma unroll
        for (int j = 0; j < 4; ++j)
            bfr[j] = *(const bf8_t*)&Bs[cur][((wn + j * 16 + l16) * 4 + xq) * 8];
#pragma unroll
        for (int i = 0; i < 4; ++i)
#pragma unroll
            for (int j = 0; j < 4; ++j)
                acc[i][j] = __builtin_amdgcn_mfma_f32_16x16x32_bf16(
                    af[i], bfr[j], acc[i][j], 0, 0, 0);
    }

    // epilogue (C layout: col = l16, row = quad*4 + r)
#pragma unroll
    for (int mi = 0; mi < 4; ++mi) {
#pragma unroll
        for (int nj = 0; nj < 4; ++nj) {
            const int gm = m0 + wm + mi * 16 + quad * 4;
            const int gn = n0 + wn + nj * 16 + l16;
            const int bb = gm >> 11, ss = gm & 2047;
            if (EPI == EPI_DOWN) {
                if (n0 < 1024) {
                    short* o = (short*)o1 + (size_t)gm * 1024 + gn;
#pragma unroll
                    for (int r = 0; r < 4; ++r) o[(size_t)r * 1024] = f2bf(acc[mi][nj][r]);
                } else if (gn < 1056) {
                    short* o = (short*)o2 + (size_t)gm * 32 + (gn - 1024);
#pragma unroll
                    for (int r = 0; r < 4; ++r) o[(size_t)r * 32] = f2bf(acc[mi][nj][r]);
                }
            } else if (EPI == EPI_WO) {
                float* o = (float*)o1 + (size_t)gm * 2048 + gn;
                float bv = bias[gn];
#pragma unroll
                for (int r = 0; r < 4; ++r) o[(size_t)r * 2048] = acc[mi][nj][r] + bv;
            } else { // EPI_UP
                if (job == 0) {
                    if (gn < 1536) {
                        int hh = gn / CDIM, cc = gn % CDIM;
                        short* o = (short*)o1 +
                            (((size_t)(bb * NH + hh) * SEQ + ss) * DHD + cc);
#pragma unroll
                        for (int r = 0; r < 4; ++r) o[(size_t)r * DHD] = f2bf(acc[mi][nj][r]);
                    } else {
                        short* o = (short*)o2 + (size_t)gm * 512 + (gn - 1536);
#pragma unroll
                        for (int r = 0; r < 4; ++r) o[(size_t)r * 512] = f2bf(acc[mi][nj][r]);
                    }
                } else {
                    if (gn < 1536) {
                        int hh = gn / CDIM, cc = gn % CDIM;
                        short* o = (short*)o3 +
                            (((size_t)(bb * NH + hh) * SEQ + ss) * DHD + cc);
#pragma unroll
                        for (int r = 0; r < 4; ++r) o[(size_t)r * DHD] = f2bf(acc[mi][nj][r]);
                    } else {
                        int n2 = gn - 1536;
                        int h2 = n2 >> 7, dh = n2 & 127;
                        size_t idx = ((size_t)(bb * NH + h2) * DHD + dh) * SEQ + ss;
                        s4_t pk = { f2bf(acc[mi][nj][0]), f2bf(acc[mi][nj][1]),
                                    f2bf(acc[mi][nj][2]), f2bf(acc[mi][nj][3]) };
                        *(s4_t*)((short*)o4 + idx) = pk;
                    }
                }
            }
        }
    }
}

// ---------------------------------------------------------------------------
// RoPE (bf16), head-major outputs [b][h][s][128]
// ---------------------------------------------------------------------------
__global__ void rope_q_kernel(const short* __restrict__ qr, short* __restrict__ qh)
{
    int idx = blockIdx.x * blockDim.x + threadIdx.x;
    int m = idx >> 9;
    int h = (idx >> 5) & 15;
    int r = idx & 31;
    int b = m >> 11, s = m & (SEQ - 1);
    float invf = expf(-((float)(2 * (r & 15)) / 32.0f) * 9.210340371976184f);
    float f = (float)s * invf;
    float cs = cosf(f), sn = sinf(f);
    float val = bf2f(qr[(size_t)m * 512 + h * 32 + r]);
    float partner = bf2f(qr[(size_t)m * 512 + h * 32 + (r ^ 16)]);
    float rot = (r < 16) ? -partner : partner;
    qh[((size_t)(b * NH + h) * SEQ + s) * DHD + CDIM + r] = f2bf(val * cs + rot * sn);
}

__global__ void rope_k_kernel(const short* __restrict__ kr, short* __restrict__ kh)
{
    int idx = blockIdx.x * blockDim.x + threadIdx.x;
    int m = idx >> 5;
    int r = idx & 31;
    int b = m >> 11, s = m & (SEQ - 1);
    float invf = expf(-((float)(2 * (r & 15)) / 32.0f) * 9.210340371976184f);
    float f = (float)s * invf;
    float cs = cosf(f), sn = sinf(f);
    float val = bf2f(kr[(size_t)m * 32 + r]);
    float partner = bf2f(kr[(size_t)m * 32 + (r ^ 16)]);
    float rot = (r < 16) ? -partner : partner;
    short o = f2bf(val * cs + rot * sn);
    short* dst = kh + ((size_t)b * NH * SEQ + s) * DHD + CDIM + r;
#pragma unroll
    for (int h = 0; h < NH; ++h) dst[(size_t)h * SEQ * DHD] = o;
}

// ---------------------------------------------------------------------------
// MFMA flash attention v4.1: BK=64, DPP softmax, exp2 domain, causal pairing.
// Mask evaluated only on the diagonal tile (wave-uniform branch).
// ---------------------------------------------------------------------------
__global__ __launch_bounds__(256)
void attn_mfma(const short* __restrict__ qh, const short* __restrict__ kh,
               const short* __restrict__ vt, short* __restrict__ ctx)
{
    const int h = blockIdx.y, b = blockIdx.z;
    __shared__ short Ks[2][8192];   // 64 keys x 128 d
    __shared__ short Vs[2][8192];   // 128 d x 64 keys
    __shared__ short Ps[4][16][72];
    const int tid  = threadIdx.x;
    const int w    = tid >> 6;
    const int lane = tid & 63;
    const int l16  = lane & 15;
    const int quad = lane >> 4;
    const float qscale = 0.12752956f;   // (1/sqrt(128)) * log2(e)

    const short* khead = kh + (size_t)(b * NH + h) * SEQ * DHD;
    const short* vhead = vt + (size_t)(b * NH + h) * DHD * SEQ;

    int koff[4], voff[4], ldso[4];
#pragma unroll
    for (int j = 0; j < 4; ++j) {
        int s = j * 256 + tid;
        int key = s >> 4, c = s & 15;
        koff[j] = key * DHD + (c ^ (key & 15)) * 8;
        int d = s >> 3, c2 = s & 7;
        voff[j] = d * SEQ + (c2 ^ (d & 7)) * 8;
        ldso[j] = (j * 256 + w * 64) * 8;
    }

    for (int phase = 0; phase < 2; ++phase) {
        const int qb = phase ? (31 - (int)blockIdx.x) : (int)blockIdx.x;
        const int q0 = qb * 64;

        bf8_t qf[4];
        {
            const short* qp = qh + ((size_t)(b * NH + h) * SEQ + q0 + w * 16 + l16) * DHD
                                 + quad * 8;
#pragma unroll
            for (int ks = 0; ks < 4; ++ks) {
                bf8_t raw = *(const bf8_t*)(qp + ks * 32);
#pragma unroll
                for (int j = 0; j < 8; ++j) qf[ks][j] = f2bf(bf2f(raw[j]) * qscale);
            }
        }

        f4_t O[8];
#pragma unroll
        for (int i = 0; i < 8; ++i) O[i] = (f4_t){0.f, 0.f, 0.f, 0.f};
        float m_run[4], l_run[4];
#pragma unroll
        for (int r = 0; r < 4; ++r) { m_run[r] = -3e38f; l_run[r] = 0.f; }

        const int ntiles = qb + 1;
        __syncthreads();   // previous phase's LDS reads done
#pragma unroll
        for (int j = 0; j < 4; ++j) {
            gload16(khead + koff[j], &Ks[0][ldso[j]]);
            gload16(vhead + voff[j], &Vs[0][ldso[j]]);
        }

        for (int t = 0; t < ntiles; ++t) {
            const int cur = t & 1;
            const int c0 = t * 64;
            __syncthreads();
            if (t + 1 < ntiles) {
                const short* kt = khead + (size_t)(c0 + 64) * DHD;
#pragma unroll
                for (int j = 0; j < 4; ++j) {
                    gload16(kt + koff[j], &Ks[cur ^ 1][ldso[j]]);
                    gload16(vhead + voff[j] + c0 + 64, &Vs[cur ^ 1][ldso[j]]);
                }
            }

            // S = Q K^T : 16 q-rows x 64 keys
            f4_t S[4];
#pragma unroll
            for (int j = 0; j < 4; ++j) S[j] = (f4_t){0.f, 0.f, 0.f, 0.f};
#pragma unroll
            for (int ks = 0; ks < 4; ++ks) {
                const int dch = ks * 4 + quad;
#pragma unroll
                for (int j = 0; j < 4; ++j) {
                    const int slot = (j * 16 + l16) * 16 + (dch ^ l16);
                    bf8_t bj = *(const bf8_t*)&Ks[cur][slot * 8];
                    S[j] = __builtin_amdgcn_mfma_f32_16x16x32_bf16(qf[ks], bj, S[j], 0, 0, 0);
                }
            }

            // online softmax, exp2 domain, DPP reductions.
            // mask only on the diagonal tile (t == ntiles-1, wave-uniform).
            const int grow0 = q0 + w * 16 + quad * 4;
            const bool diag = (t == ntiles - 1);
            float alpha[4];
#pragma unroll
            for (int r = 0; r < 4; ++r) {
                float sv[4];
                if (diag) {
                    const int grow = grow0 + r;
#pragma unroll
                    for (int j = 0; j < 4; ++j)
                        sv[j] = (c0 + j * 16 + l16 <= grow) ? S[j][r] : -3e38f;
                } else {
#pragma unroll
                    for (int j = 0; j < 4; ++j) sv[j] = S[j][r];
                }
                float mx = fmaxf(fmaxf(sv[0], sv[1]), fmaxf(sv[2], sv[3]));
                mx = dpp_max16(mx);
                const float mnew = fmaxf(m_run[r], mx);
                alpha[r] = __builtin_amdgcn_exp2f(m_run[r] - mnew);
                float p0 = __builtin_amdgcn_exp2f(sv[0] - mnew);
                float p1 = __builtin_amdgcn_exp2f(sv[1] - mnew);
                float p2 = __builtin_amdgcn_exp2f(sv[2] - mnew);
                float p3 = __builtin_amdgcn_exp2f(sv[3] - mnew);
                float rs = dpp_sum16((p0 + p1) + (p2 + p3));
                l_run[r] = alpha[r] * l_run[r] + rs;
                m_run[r] = mnew;
                short* pr = &Ps[w][quad * 4 + r][l16];
                pr[0]  = f2bf(p0);
                pr[16] = f2bf(p1);
                pr[32] = f2bf(p2);
                pr[48] = f2bf(p3);
            }

#pragma unroll
            for (int dt = 0; dt < 8; ++dt)
#pragma unroll
                for (int r = 0; r < 4; ++r) O[dt][r] *= alpha[r];

            // PV
#pragma unroll
            for (int ks2 = 0; ks2 < 2; ++ks2) {
                bf8_t pf = *(const bf8_t*)&Ps[w][l16][ks2 * 32 + quad * 8];
#pragma unroll
                for (int dt = 0; dt < 8; ++dt) {
                    const int d = dt * 16 + l16;
                    const int slot = d * 8 + ((ks2 * 4 + quad) ^ (d & 7));
                    bf8_t vf = *(const bf8_t*)&Vs[cur][slot * 8];
                    O[dt] = __builtin_amdgcn_mfma_f32_16x16x32_bf16(pf, vf, O[dt], 0, 0, 0);
                }
            }
        }

        float inv_l[4];
#pragma unroll
        for (int r = 0; r < 4; ++r) inv_l[r] = 1.0f / l_run[r];
        short* cbase = ctx + (size_t)(b * SEQ + q0 + w * 16 + quad * 4) * HIDN
                           + h * DHD + l16;
#pragma unroll
        for (int r = 0; r < 4; ++r)
#pragma unroll
            for (int dt = 0; dt < 8; ++dt)
                cbase[(size_t)r * HIDN + dt * 16] = f2bf(O[dt][r] * inv_l[r]);
    }
}

// ---------------------------------------------------------------------------
extern "C" void kernel_launch(void* const* d_in, const int* in_sizes, int n_in,
                              void* d_out, int out_size, void* d_ws, size_t ws_size,
                              hipStream_t stream)
{
    const float* x        = (const float*)d_in[0];
    const float* Wq_down  = (const float*)d_in[1];
    const float* Wq_up    = (const float*)d_in[2];
    const float* Wq_rope  = (const float*)d_in[3];
    const float* Wkv_down = (const float*)d_in[4];
    const float* Wk_up    = (const float*)d_in[5];
    const float* Wk_rope  = (const float*)d_in[6];
    const float* Wv_up    = (const float*)d_in[7];
    const float* Wo       = (const float*)d_in[8];
    const float* bo       = (const float*)d_in[9];
    float* out = (float*)d_out;

    // workspace (bf16 shorts)
    short* ws     = (short*)d_ws;
    short* xb     = ws;                 //  8388608
    short* wdownc = ws + 8388608;       //  2162688  [Wq_down|Wkv_down|Wk_rope] 1056 rows
    short* wqur   = ws + 10551296;      //  1048576  [Wq_up | Wq_rope]
    short* wkvu   = ws + 11599872;      //  1835008  [Wk_up | Wv_up]
    short* wob    = ws + 13434880;      //  4194304
    short* qkvlat = ws + 17629184;      //  4194304  [4096][1024] = qlat|kvlat
    short* qhb    = ws + 21823488;      //  8388608  [b][h][s][128]
    short* khb    = ws + 30212096;      //  8388608  [b][h][s][128]
    short* vtw    = ws + 38600704;      //  8388608  [b][h][d][s]
    short* ctxb   = ws + 46989312;      //  8388608  [b][s][2048]
    short* qrt    = ws + 55377920;      //  2097152
    short* krt    = ws + 57475072;      //   131072

    dim3 blk(256);
    cvt_all<<<dim3(8608), blk, 0, stream>>>(
        x, Wq_down, Wq_up, Wq_rope, Wkv_down, Wk_up, Wk_rope, Wv_up, Wo,
        xb, wdownc, wqur, wqur + 786432, wdownc + 1048576,
        wkvu, wdownc + 2097152, wkvu + 786432, wob);

    gemm_t<2048, EPI_DOWN><<<dim3(32, 9), blk, 0, stream>>>(
        xb, wdownc, nullptr, qkvlat, krt, nullptr, nullptr, nullptr);
    gemm_t<512, EPI_UP><<<dim3(32, 44), blk, 0, stream>>>(
        qkvlat, wqur, wkvu, qhb, qrt, khb, vtw, nullptr);

    rope_q_kernel<<<dim3(MTOT * NH * RD / 256), blk, 0, stream>>>(qrt, qhb);
    rope_k_kernel<<<dim3(MTOT * RD / 256), blk, 0, stream>>>(krt, khb);

    attn_mfma<<<dim3(16, NH, NB), blk, 0, stream>>>(qhb, khb, vtw, ctxb);

    gemm_t<2048, EPI_WO><<<dim3(32, 16), blk, 0, stream>>>(
        ctxb, wob, nullptr, out, nullptr, nullptr, nullptr, bo);
}